// Round 11
// baseline (210.202 us; speedup 1.0000x reference)
//
#include <hip/hip_runtime.h>
#include <hip/hip_bf16.h>

// NSA forward, MI355X round 11. All inputs fp32, output fp32.
// attn_k phase loop is BARRIER-FREE: prep_k precomputes per-lane MFMA
// B-fragments for K and V (16B/lane coalesced global loads, L2-resident),
// P round-trip stays in wave-private LDS (same-wave DS ops are in-order).
// Role-split grid 1024, XCD swizzle, slcbuf+merge epilogue.
// Shapes: S=4096, seqlen=2048, qh=8, kvh=2, dim=128, blk=64, TOPK=16,
// window=(512,0).

#define SEQ   2048
#define NB    2
#define KV    2
#define NH    4
#define QH    8
#define DIM   128
#define NBLK  32
#define NQB   32
#define NTOP  16
#define SCALE 0.08838834764831845f   // 128^-0.5
#define QS    36                     // cmp LDS quarter stride (floats)
#define RS    144                    // cmp LDS row stride
#define VP    72                     // P LDS row stride (bf16)
#define TP    72                     // prep transpose-tile row stride

typedef unsigned short ushort_t;
using bf16x8 = __attribute__((ext_vector_type(8))) short;
using f32x4  = __attribute__((ext_vector_type(4))) float;

__device__ __forceinline__ unsigned pkbf(float a, float b){
  union { __hip_bfloat162 h; unsigned u; } cv;
  cv.h = __float22bfloat162_rn(make_float2(a, b));
  return cv.u;
}
__device__ __forceinline__ ushort_t f2b(float f){
  union { float f; unsigned i; } x; x.f = f;
  unsigned r = x.i + 0x7fffu + ((x.i >> 16) & 1u);   // RNE
  return (ushort_t)(r >> 16);
}

// ---------------- kernel 0: K/V -> MFMA B-fragment preprocessing ------------
// Kfrag[((bbg*32+n)*16 + kc*4+nt)*64 + lane] = bf16x8 of
//   K[key = n*64+nt*16+(lane&15)][d = kc*32+(lane>>4)*8 .. +7]
// Vfrag[((bbg*32+n)*16 + kc2*8+dt)*64 + lane] = bf16x8 of
//   V[key = n*64+kc2*32+(lane>>4)*8+j][d = dt*16+(lane&15)]  (transposed)
// grid 128 = bbg(4) x n(32); 256 threads.
__global__ __launch_bounds__(256) void prep_k(
    const float* __restrict__ k, const float* __restrict__ v,
    ushort_t* __restrict__ Kfrag, ushort_t* __restrict__ Vfrag)
{
  int blk = blockIdx.x;
  int n = blk & 31, bbg = blk >> 5;
  int bb = bbg >> 1, g = bbg & 1;
  int tid = threadIdx.x;
  __shared__ ushort_t TT[128*TP];   // [d][key] transposed V tile, 18 KB

  // K fragments: direct (each chunk = contiguous 16B of a K row)
  size_t kout = ((size_t)(bbg*NBLK + n)*16)*64*8;   // ushort units
#pragma unroll
  for (int jj = 0; jj < 4; ++jj){
    int o = tid + jj*256;              // 1024 chunks = 16 frags x 64 lanes
    int f = o >> 6, l = o & 63;
    int kc = f >> 2, nt = f & 3;
    int key = nt*16 + (l & 15);
    int d0  = kc*32 + (l >> 4)*8;
    const float* src = k + ((size_t)(bb*SEQ + n*64 + key)*KV + g)*DIM + d0;
    float4 u0 = *(const float4*)src;
    float4 u1 = *(const float4*)(src + 4);
    uint4 pk;
    pk.x = pkbf(u0.x,u0.y); pk.y = pkbf(u0.z,u0.w);
    pk.z = pkbf(u1.x,u1.y); pk.w = pkbf(u1.z,u1.w);
    *(uint4*)&Kfrag[kout + (size_t)o*8] = pk;
  }

  // V transpose tile into LDS
#pragma unroll
  for (int jj = 0; jj < 8; ++jj){
    int i = tid + jj*256;              // 2048 float4 units = 64 keys x 32
    int key = i >> 5, ds = i & 31;
    size_t src = ((size_t)(bb*SEQ + n*64 + key)*KV + g)*DIM + ds*4;
    float4 vx = *(const float4*)(v + src);
    unsigned v01 = pkbf(vx.x,vx.y), v23 = pkbf(vx.z,vx.w);
    TT[(ds*4+0)*TP + key] = (ushort_t)(v01 & 0xffffu);
    TT[(ds*4+1)*TP + key] = (ushort_t)(v01 >> 16);
    TT[(ds*4+2)*TP + key] = (ushort_t)(v23 & 0xffffu);
    TT[(ds*4+3)*TP + key] = (ushort_t)(v23 >> 16);
  }
  __syncthreads();

  // V fragments from the transposed tile (contiguous 16B per chunk)
  size_t vout = ((size_t)(bbg*NBLK + n)*16)*64*8;
#pragma unroll
  for (int jj = 0; jj < 4; ++jj){
    int o = tid + jj*256;
    int f = o >> 6, l = o & 63;
    int kc2 = f >> 3, dt = f & 7;
    int d    = dt*16 + (l & 15);
    int key0 = kc2*32 + (l >> 4)*8;
    uint4 u = *(uint4*)&TT[d*TP + key0];
    *(uint4*)&Vfrag[vout + (size_t)o*8] = u;
  }
}

// ---------------- kernel 1: block compression (fp32 out to ws) --------------
__global__ __launch_bounds__(256) void compress_k(
    const float* __restrict__ k, const float* __restrict__ v,
    const float* __restrict__ w_k, const float* __restrict__ b_k,
    const float* __restrict__ w_v, const float* __restrict__ b_v,
    float* __restrict__ Kc, float* __restrict__ Vc)
{
  int blk = blockIdx.x;            // (bb,g,n,dhalf)
  int dh = blk & 1;
  int n  = (blk >> 1) & 31;
  int g  = (blk >> 6) & 1;
  int bb = blk >> 7;
  int tid = threadIdx.x;

  __shared__ float wks[64], wvs[64];
  __shared__ float accK[16][64], accV[16][64];
  if (tid < 64){ wks[tid] = w_k[tid]; wvs[tid] = w_v[tid]; }
  __syncthreads();

  int r4 = tid >> 4, dq = tid & 15;
  float4 sk = {0,0,0,0}, sv = {0,0,0,0};
  for (int rr = 0; rr < 4; ++rr){
    int row = r4*4 + rr;
    size_t off = ((size_t)(bb*SEQ + n*64 + row)*KV + g)*DIM + dh*64 + dq*4;
    float4 kx = *(const float4*)(k + off);
    float4 vx = *(const float4*)(v + off);
    float a = wks[row], b = wvs[row];
    sk.x += a*kx.x; sk.y += a*kx.y; sk.z += a*kx.z; sk.w += a*kx.w;
    sv.x += b*vx.x; sv.y += b*vx.y; sv.z += b*vx.z; sv.w += b*vx.w;
  }
  *(float4*)&accK[r4][dq*4] = sk;
  *(float4*)&accV[r4][dq*4] = sv;
  __syncthreads();
  size_t obase = ((size_t)((bb*KV+g)*NBLK + n))*DIM + dh*64;
  if (tid < 64){
    float s = 0.f;
#pragma unroll
    for (int i = 0; i < 16; ++i) s += accK[i][tid];
    Kc[obase + tid] = s + b_k[0];
  } else if (tid < 128){
    int d = tid - 64;
    float s = 0.f;
#pragma unroll
    for (int i = 0; i < 16; ++i) s += accV[i][d];
    Vc[obase + d] = s + b_v[0];
  }
}

// ------- kernel 2: compressed attention (fp32 VALU; exact pooled P) ---------
__global__ __launch_bounds__(256) void cmp_attn_k(
    const float* __restrict__ q, const float* __restrict__ Kc,
    const float* __restrict__ Vc,
    const float* __restrict__ w_gate, const float* __restrict__ b_gate,
    float* __restrict__ pooled_part, float* __restrict__ out)
{
  int blk = blockIdx.x;
  int h  = blk & 3;
  int qb = (blk >> 2) & (NQB-1);
  int g  = (blk >> 7) & 1;
  int bb = blk >> 8;
  int tid = threadIdx.x;
  int qi = tid >> 2, c = tid & 3;

  __shared__ float Ks[32*RS];
  __shared__ float Vs[32*RS];
  __shared__ float wsum[4][NBLK];

  const float4* Ksrc = (const float4*)(Kc + (size_t)(bb*KV + g) * NBLK * DIM);
  const float4* Vsrc = (const float4*)(Vc + (size_t)(bb*KV + g) * NBLK * DIM);
  for (int i = tid; i < 1024; i += 256){
    int row = i >> 5, seg = i & 31;
    int dst = row*RS + (seg>>3)*QS + (seg&7)*4;
    ((float4*)(Ks+dst))[0] = Ksrc[i];
    ((float4*)(Vs+dst))[0] = Vsrc[i];
  }
  __syncthreads();

  int row = bb*SEQ + qb*64 + qi;
  float qv[32];
  {
    const float4* q4 = (const float4*)(q + ((size_t)row*QH + g*NH + h)*DIM + c*32);
#pragma unroll
    for (int j = 0; j < 8; ++j){
      float4 u = q4[j];
      qv[4*j+0]=u.x; qv[4*j+1]=u.y; qv[4*j+2]=u.z; qv[4*j+3]=u.w;
    }
  }

  float gp = 0.f;
#pragma unroll
  for (int d = 0; d < 32; ++d) gp += qv[d]*w_gate[(c*32+d)*3 + 0];
  gp += __shfl_xor(gp, 1); gp += __shfl_xor(gp, 2);
  float g0 = 1.f/(1.f + expf(-(gp + b_gate[0])));

  float sc[NBLK];
#pragma unroll
  for (int n = 0; n < NBLK; ++n){
    float p = 0.f;
    const float4* kr = (const float4*)(Ks + n*RS + c*QS);
#pragma unroll
    for (int j = 0; j < 8; ++j){
      float4 u = kr[j];
      p += qv[4*j+0]*u.x + qv[4*j+1]*u.y + qv[4*j+2]*u.z + qv[4*j+3]*u.w;
    }
    p += __shfl_xor(p, 1); p += __shfl_xor(p, 2);
    sc[n] = p * SCALE;
  }
  float m = sc[0];
#pragma unroll
  for (int n = 1; n < NBLK; ++n) m = fmaxf(m, sc[n]);
  float l = 0.f;
#pragma unroll
  for (int n = 0; n < NBLK; ++n){ sc[n] = expf(sc[n]-m); l += sc[n]; }
  float inv = 1.f/l;
#pragma unroll
  for (int n = 0; n < NBLK; ++n) sc[n] *= inv;

#pragma unroll
  for (int n = 0; n < NBLK; ++n){
    float t2 = sc[n];
    t2 += __shfl_xor(t2, 4); t2 += __shfl_xor(t2, 8);
    t2 += __shfl_xor(t2, 16); t2 += __shfl_xor(t2, 32);
    if ((tid & 63) == 0) wsum[tid>>6][n] = t2;
  }
  __syncthreads();
  if (tid < NBLK)
    pooled_part[(size_t)blk*NBLK + tid] =
        (wsum[0][tid]+wsum[1][tid]) + (wsum[2][tid]+wsum[3][tid]);

  float o[32];
#pragma unroll
  for (int d = 0; d < 32; ++d) o[d] = 0.f;
#pragma unroll
  for (int n = 0; n < NBLK; ++n){
    float pb = sc[n];
    const float4* vr = (const float4*)(Vs + n*RS + c*QS);
#pragma unroll
    for (int j = 0; j < 8; ++j){
      float4 u = vr[j];
      o[4*j+0] += pb*u.x; o[4*j+1] += pb*u.y;
      o[4*j+2] += pb*u.z; o[4*j+3] += pb*u.w;
    }
  }
  float* op = out + ((size_t)row*QH + g*NH + h)*DIM + c*32;
#pragma unroll
  for (int d = 0; d < 32; ++d) op[d] = g0*o[d];   // overwrite (first branch)
}

// ---- kernel 3: role-split topk+slc | win attention (MFMA, barrier-free) ----
// grid 1024; idx&7 encodes (bb,g) twice -> same-(bb,g) blocks share XCDs.
// B-operands load straight from Kfrag/Vfrag (global, 16B/lane, L2-resident).
// Layouts (m89/m91/m120): A[m=lane&15][k=quad*8+j], B[k=quad*8+j][n=lane&15],
// C[col=lane&15,row=quad*4+r]
__global__ __launch_bounds__(256, 2) void attn_k(
    const float* __restrict__ q, const ushort_t* __restrict__ Kfrag,
    const ushort_t* __restrict__ Vfrag, const float* __restrict__ pp,
    const float* __restrict__ w_gate, const float* __restrict__ b_gate,
    float* __restrict__ slcbuf, float* __restrict__ out)
{
  int idx = blockIdx.x;
  int x = idx & 7, low = idx & 1, u = idx >> 3;
  int bbg = x >> 1;                 // (bb,g)
  int j = u*2 + low;                // 0..255
  int role = j >> 7;                // 0 = slc, 1 = win
  int qb = (j >> 2) & 31;
  int h  = j & 3;
  int bb = bbg >> 1, g = bbg & 1;

  int tid = threadIdx.x;
  int lane = tid & 63, w = tid >> 6, quad = lane >> 4, l15 = lane & 15;

  __shared__ short Ps[64*VP];     // 9.2 KB, wave-private regions
  __shared__ float gbuf[64];
  __shared__ int   idxs[NTOP];

  // ---- top-k (role 0 only; wave 0; lax.top_k tie rule) ----
  if (role == 0 && tid < 64){
    int n = lane;
    float val = -INFINITY;
    if (n < NBLK){
      const float* p0 = pp + ((size_t)((bb*KV+g)*NQB + qb)*NH)*NBLK + n;
      val = (p0[0] + p0[NBLK]) + (p0[2*NBLK] + p0[3*NBLK]);
    }
    for (int t = 0; t < NTOP; ++t){
      float bv = val; int bi = n;
      for (int mm = 1; mm < 32; mm <<= 1){
        float ov = __shfl_xor(bv, mm);
        int   oi = __shfl_xor(bi, mm);
        if (ov > bv || (ov == bv && oi < bi)){ bv = ov; bi = oi; }
      }
      if (lane == 0) idxs[t] = bi;
      if (n == bi) val = -INFINITY;
    }
  }

  // ---- Q fragments direct from global + exact fp32 gate (role-selected) ----
  const float* qrow = q + ((size_t)(bb*SEQ + qb*64 + w*16 + l15)*QH + g*NH + h)*DIM;
  int gcol = 1 + role;
  bf16x8 qfrag[4];
  float gp = 0.f;
#pragma unroll
  for (int kc = 0; kc < 4; ++kc){
    int d0 = kc*32 + quad*8;
    float4 u0 = *(const float4*)(qrow + d0);
    float4 u1 = *(const float4*)(qrow + d0 + 4);
    float qf[8] = {u0.x,u0.y,u0.z,u0.w,u1.x,u1.y,u1.z,u1.w};
#pragma unroll
    for (int jj = 0; jj < 8; ++jj) gp += qf[jj]*w_gate[(d0+jj)*3 + gcol];
    union { unsigned uu[4]; bf16x8 v8; } tq;
    tq.uu[0] = pkbf(u0.x,u0.y); tq.uu[1] = pkbf(u0.z,u0.w);
    tq.uu[2] = pkbf(u1.x,u1.y); tq.uu[3] = pkbf(u1.z,u1.w);
    qfrag[kc] = tq.v8;
  }
  gp += __shfl_xor(gp,16); gp += __shfl_xor(gp,32);
  if (quad == 0) gbuf[w*16+l15] = 1.f/(1.f + __expf(-(gp + b_gate[gcol])));
  __syncthreads();   // publishes gbuf + idxs (the ONLY block barrier)
  float gl[4];
#pragma unroll
  for (int r = 0; r < 4; ++r) gl[r] = gbuf[w*16+quad*4+r];

  const bf16x8* kfb = (const bf16x8*)Kfrag + (size_t)bbg*NBLK*16*64;
  const bf16x8* vfb = (const bf16x8*)Vfrag + (size_t)bbg*NBLK*16*64;

  int kb0 = (qb >= 8) ? (qb - 8) : 0;
  int nph = (role == 0) ? NTOP : (qb - kb0 + 1);

  float m1[4], l1[4];
  f32x4 oacc[8];
  const f32x4 zero4 = {0.f,0.f,0.f,0.f};
#pragma unroll
  for (int r = 0; r < 4; ++r){ m1[r] = -INFINITY; l1[r] = 0.f; }
#pragma unroll
  for (int dt = 0; dt < 8; ++dt) oacc[dt] = zero4;

  for (int t = 0; t < nph; ++t){
    int kb = (role == 0) ? idxs[t] : (kb0 + t);
    const bf16x8* kf = kfb + (size_t)kb*16*64;
    const bf16x8* vf = vfb + (size_t)kb*16*64;

    f32x4 sacc[4];
#pragma unroll
    for (int nt = 0; nt < 4; ++nt) sacc[nt] = zero4;
#pragma unroll
    for (int kc = 0; kc < 4; ++kc){
      bf16x8 a = qfrag[kc];
#pragma unroll
      for (int nt = 0; nt < 4; ++nt){
        bf16x8 b = kf[(kc*4+nt)*64 + lane];
        sacc[nt] = __builtin_amdgcn_mfma_f32_16x16x32_bf16(a, b, sacc[nt], 0, 0, 0);
      }
    }

    bool mlow  = (role == 1) && (kb == qb - 8);   // valid: key >= qi
    bool mhigh = (role == 1) && (kb == qb);       // valid: key <= qi
    float alpha[4];
#pragma unroll
    for (int r = 0; r < 4; ++r){
      int qi_local = w*16 + quad*4 + r;
      float mx = -INFINITY;
#pragma unroll
      for (int nt = 0; nt < 4; ++nt){
        int key = nt*16 + l15;
        float sv = sacc[nt][r]*SCALE;
        bool valid = (!mlow || key >= qi_local) && (!mhigh || key <= qi_local);
        sv = valid ? sv : -INFINITY;
        sacc[nt][r] = sv;
        mx = fmaxf(mx, sv);
      }
      mx = fmaxf(mx, __shfl_xor(mx,1)); mx = fmaxf(mx, __shfl_xor(mx,2));
      mx = fmaxf(mx, __shfl_xor(mx,4)); mx = fmaxf(mx, __shfl_xor(mx,8));
      float mn = fmaxf(m1[r], mx);
      alpha[r] = __expf(m1[r] - mn);
      float s0 = 0.f;
#pragma unroll
      for (int nt = 0; nt < 4; ++nt){
        float pe = __expf(sacc[nt][r] - mn);   // masked -> 0
        sacc[nt][r] = pe;
        s0 += pe;
      }
      s0 += __shfl_xor(s0,1); s0 += __shfl_xor(s0,2);
      s0 += __shfl_xor(s0,4); s0 += __shfl_xor(s0,8);
      l1[r] = l1[r]*alpha[r] + s0;
      m1[r] = mn;
    }
    // P: C-layout -> A-layout via wave-private LDS (same-wave DS ops
    // are processed in order; no block barrier needed)
#pragma unroll
    for (int nt = 0; nt < 4; ++nt)
#pragma unroll
      for (int r = 0; r < 4; ++r)
        Ps[(w*16 + quad*4 + r)*VP + nt*16 + l15] = (short)f2b(sacc[nt][r]);
#pragma unroll
    for (int dt = 0; dt < 8; ++dt)
#pragma unroll
      for (int r = 0; r < 4; ++r) oacc[dt][r] *= alpha[r];
#pragma unroll
    for (int kc2 = 0; kc2 < 2; ++kc2){
      bf16x8 pa = *(bf16x8*)&Ps[(w*16 + l15)*VP + kc2*32 + quad*8];
#pragma unroll
      for (int dt = 0; dt < 8; ++dt){
        bf16x8 vb8 = vf[(kc2*8+dt)*64 + lane];
        oacc[dt] = __builtin_amdgcn_mfma_f32_16x16x32_bf16(pa, vb8, oacc[dt], 0, 0, 0);
      }
    }
  }

  // ---- epilogue: race-free plain stores ----
#pragma unroll
  for (int r = 0; r < 4; ++r){
    float s2 = gl[r] / l1[r];
    size_t ob = ((size_t)(bb*SEQ + qb*64 + w*16 + quad*4 + r)*QH + g*NH + h)*DIM + l15;
    if (role == 0){
      float* op = slcbuf + ob;              // unique writer; full coverage
#pragma unroll
      for (int dt = 0; dt < 8; ++dt) op[dt*16] = s2 * oacc[dt][r];
    } else {
      float* op = out + ob;                 // unique writer; cmp already done
#pragma unroll
      for (int dt = 0; dt < 8; ++dt) op[dt*16] += s2 * oacc[dt][r];
    }
  }
}

// ---------------- kernel 4: merge (out += slcbuf) ---------------------------
__global__ __launch_bounds__(256) void merge_k(const float* __restrict__ slcbuf,
                                               float* __restrict__ out){
  int i = blockIdx.x * 256 + threadIdx.x;   // over 4096*8*128/4 float4s
  float4 a = ((const float4*)slcbuf)[i];
  float4 b = ((float4*)out)[i];
  b.x += a.x; b.y += a.y; b.z += a.z; b.w += a.w;
  ((float4*)out)[i] = b;
}

extern "C" void kernel_launch(void* const* d_in, const int* in_sizes, int n_in,
                              void* d_out, int out_size, void* d_ws, size_t ws_size,
                              hipStream_t stream) {
  const float* q      = (const float*)d_in[0];
  const float* k      = (const float*)d_in[1];
  const float* v      = (const float*)d_in[2];
  const float* w_k    = (const float*)d_in[3];
  const float* b_k    = (const float*)d_in[4];
  const float* w_v    = (const float*)d_in[5];
  const float* b_v    = (const float*)d_in[6];
  const float* w_gate = (const float*)d_in[7];
  const float* b_gate = (const float*)d_in[8];
  float* out = (float*)d_out;

  float* ws       = (float*)d_ws;
  float* Kc       = ws;                        // 16384 f32
  float* Vc       = ws + 16384;                // 16384 f32
  float* pp       = ws + 32768;                // 512*32 f32
  float* slcbuf   = ws + 49152;                // 4.19M f32 (16.8 MB)
  ushort_t* Kfrag = (ushort_t*)(ws + 4243456); // 4*32*16*64*8 bf16 (2 MB)
  ushort_t* Vfrag = Kfrag + 1048576;           // 2 MB

  prep_k    <<<128, 256, 0, stream>>>(k, v, Kfrag, Vfrag);
  compress_k<<<256, 256, 0, stream>>>(k, v, w_k, b_k, w_v, b_v, Kc, Vc);
  cmp_attn_k<<<NB*KV*NQB*NH, 256, 0, stream>>>(q, Kc, Vc, w_gate, b_gate, pp, out);
  attn_k    <<<1024, 256, 0, stream>>>(q, Kfrag, Vfrag, pp, w_gate, b_gate, slcbuf, out);
  merge_k   <<<4096, 256, 0, stream>>>(slcbuf, out);
}